// Round 1
// baseline (21.480 us; speedup 1.0000x reference)
//
#include <hip/hip_runtime.h>

// ColorTransform: per-pixel degree-3 polynomial feature expansion (19 monomials
// of 3 channels) followed by a 19->3 linear map + bias.
// x: [B=16, C=3, H=512, W=512] f32; weight: [19,3] f32; bias: [3] f32.
// Memory-bound: ~100 MB traffic -> ~16 us roofline at 6.3 TB/s.

constexpr int HW = 512 * 512;          // pixels per (b, c) plane
constexpr int LOG2_HW = 18;

__device__ __forceinline__ float rfl(float v) {
    // Force a wave-uniform value into an SGPR (keeps the 57 weights + 3 bias
    // out of the VGPR budget; v_fma can take one SGPR operand).
    return __uint_as_float(__builtin_amdgcn_readfirstlane(__float_as_uint(v)));
}

__global__ __launch_bounds__(256) void ct_kernel(
    const float* __restrict__ x, const float* __restrict__ wgt,
    const float* __restrict__ bias, float* __restrict__ out, int ngroups)
{
    // Uniform (scalar) copies of the 19x3 weight matrix + bias.
    float w[57];
#pragma unroll
    for (int i = 0; i < 57; ++i) w[i] = rfl(wgt[i]);
    const float b0 = rfl(bias[0]);
    const float b1 = rfl(bias[1]);
    const float b2 = rfl(bias[2]);

    const int tid = blockIdx.x * blockDim.x + threadIdx.x;
    const int nthreads = gridDim.x * blockDim.x;

    for (int g = tid; g < ngroups; g += nthreads) {
        const int p  = g << 2;               // flat pixel index (4 px / thread)
        const int b  = p >> LOG2_HW;         // batch index (HW = 2^18)
        const int hw = p & (HW - 1);

        const float* base = x + (size_t)b * 3 * HW + hw;
        float r0[4], r1[4], r2[4];
        *reinterpret_cast<float4*>(r0) = *reinterpret_cast<const float4*>(base);
        *reinterpret_cast<float4*>(r1) = *reinterpret_cast<const float4*>(base + HW);
        *reinterpret_cast<float4*>(r2) = *reinterpret_cast<const float4*>(base + 2 * HW);

        float o0[4], o1[4], o2[4];
#pragma unroll
        for (int j = 0; j < 4; ++j) {
            const float a = r0[j], bch = r1[j], c = r2[j];
            // 19 monomials, exact reference order & association:
            float f[19];
            f[0]  = a;          f[1]  = bch;        f[2]  = c;
            f[3]  = a * a;      f[4]  = a * bch;    f[5]  = a * c;
            f[6]  = bch * bch;  f[7]  = bch * c;    f[8]  = c * c;
            f[9]  = a * f[3];   f[10] = a * f[4];   f[11] = a * f[5];
            f[12] = a * f[6];   f[13] = a * f[7];   f[14] = a * f[8];
            f[15] = bch * f[6]; f[16] = bch * f[7]; f[17] = bch * f[8];
            f[18] = c * f[8];

            float s0 = b0, s1 = b1, s2 = b2;
#pragma unroll
            for (int k = 0; k < 19; ++k) {
                s0 = fmaf(f[k], w[3 * k + 0], s0);
                s1 = fmaf(f[k], w[3 * k + 1], s1);
                s2 = fmaf(f[k], w[3 * k + 2], s2);
            }
            o0[j] = s0; o1[j] = s1; o2[j] = s2;
        }

        float* obase = out + (size_t)b * 3 * HW + hw;
        *reinterpret_cast<float4*>(obase)          = *reinterpret_cast<const float4*>(o0);
        *reinterpret_cast<float4*>(obase + HW)     = *reinterpret_cast<const float4*>(o1);
        *reinterpret_cast<float4*>(obase + 2 * HW) = *reinterpret_cast<const float4*>(o2);
    }
}

extern "C" void kernel_launch(void* const* d_in, const int* in_sizes, int n_in,
                              void* d_out, int out_size, void* d_ws, size_t ws_size,
                              hipStream_t stream) {
    const float* x    = (const float*)d_in[0];   // [16,3,512,512]
    const float* wgt  = (const float*)d_in[1];   // [19,3]
    const float* bias = (const float*)d_in[2];   // [3]
    // d_in[3] = degree (int, ==3) — baked into the kernel.
    float* out = (float*)d_out;

    const int npix    = in_sizes[0] / 3;         // B*H*W = 4,194,304
    const int ngroups = npix / 4;                // 4 pixels per thread-iter

    const int block = 256;
    const int grid  = 2048;                      // grid-stride, ~2 iters/thread
    ct_kernel<<<grid, block, 0, stream>>>(x, wgt, bias, out, ngroups);
}